// Round 1
// baseline (542.708 us; speedup 1.0000x reference)
//
#include <hip/hip_runtime.h>

#define DIM    256
#define NCODES 1024
#define BATCH  16
#define SEQ    2048
#define NROWS  (BATCH * SEQ)   // 32768
#define MROWS  16
#define NTHR   256

__device__ __forceinline__ float wave_reduce_sum(float s) {
#pragma unroll
  for (int off = 32; off > 0; off >>= 1) s += __shfl_down(s, off, 64);
  return s;
}

// Transpose codebook [K][D] -> WT [D][K] and compute cb_sq[k] = ||w_k||^2.
__global__ __launch_bounds__(NTHR) void k_prep(const float* __restrict__ cb,
                                               float* __restrict__ wt,
                                               float* __restrict__ cbsq) {
  const int k = blockIdx.x;   // code
  const int t = threadIdx.x;  // dim
  const float v = cb[k * DIM + t];
  wt[t * NCODES + k] = v;
  float s = wave_reduce_sum(v * v);
  __shared__ float red[NTHR / 64];
  if ((t & 63) == 0) red[t >> 6] = s;
  __syncthreads();
  if (t == 0) cbsq[k] = red[0] + red[1] + red[2] + red[3];
}

// denom[b] = sum(mask[b,:]) ; zero the per-batch loss accumulators.
__global__ __launch_bounds__(NTHR) void k_mask(const float* __restrict__ mask,
                                               float* __restrict__ denom,
                                               float* __restrict__ lsum) {
  const int b = blockIdx.x;
  const int t = threadIdx.x;
  float s = 0.f;
  for (int i = t; i < SEQ; i += NTHR) s += mask[b * SEQ + i];
  s = wave_reduce_sum(s);
  __shared__ float red[NTHR / 64];
  if ((t & 63) == 0) red[t >> 6] = s;
  __syncthreads();
  if (t == 0) { denom[b] = red[0] + red[1] + red[2] + red[3]; lsum[b] = 0.f; }
}

// For a block of MROWS rows, compute argmin_k (||w_k||^2 - 2 x·w_k).
// Thread = one code column per code-tile; feat reads are wave-uniform -> s_load.
__global__ __launch_bounds__(NTHR) void k_argmin(const float* __restrict__ feat,
                                                 const float* __restrict__ wt,
                                                 const float* __restrict__ cbsq,
                                                 int* __restrict__ idx_out) {
  const int row0 = blockIdx.x * MROWS;
  const int c = threadIdx.x;

  float best[MROWS];
  int bestk[MROWS];
#pragma unroll
  for (int r = 0; r < MROWS; ++r) { best[r] = 3.4e38f; bestk[r] = 0; }

  const float* __restrict__ frow = feat + (size_t)row0 * DIM;

  for (int ct = 0; ct < NCODES / NTHR; ++ct) {
    const int code = ct * NTHR + c;
    float acc[MROWS];
#pragma unroll
    for (int r = 0; r < MROWS; ++r) acc[r] = 0.f;
    const float* __restrict__ wcol = wt + code;
#pragma unroll 4
    for (int d = 0; d < DIM; ++d) {
      const float w = wcol[(size_t)d * NCODES];  // coalesced vector load (L2-resident)
#pragma unroll
      for (int r = 0; r < MROWS; ++r)
        acc[r] = fmaf(frow[r * DIM + d], w, acc[r]);  // frow[..] uniform -> SGPR operand
    }
    const float cs = cbsq[code];
#pragma unroll
    for (int r = 0; r < MROWS; ++r) {
      const float dist = fmaf(-2.f, acc[r], cs);
      if (dist < best[r]) { best[r] = dist; bestk[r] = code; }  // strict <: earliest code wins
    }
  }

  // Block-level argmin reduce, per row; tie-break on smaller index.
  __shared__ float s_min[MROWS][NTHR];
  __shared__ int s_idx[MROWS][NTHR];
#pragma unroll
  for (int r = 0; r < MROWS; ++r) { s_min[r][c] = best[r]; s_idx[r][c] = bestk[r]; }
  __syncthreads();
  for (int stride = NTHR / 2; stride > 0; stride >>= 1) {
    if (c < stride) {
#pragma unroll
      for (int r = 0; r < MROWS; ++r) {
        const float m1 = s_min[r][c], m2 = s_min[r][c + stride];
        const int i1 = s_idx[r][c], i2 = s_idx[r][c + stride];
        if (m2 < m1 || (m2 == m1 && i2 < i1)) { s_min[r][c] = m2; s_idx[r][c] = i2; }
      }
    }
    __syncthreads();
  }
  if (c < MROWS) idx_out[row0 + c] = s_idx[c][0];
}

// Gather codes, write straight-through output, accumulate masked squared error.
__global__ __launch_bounds__(NTHR) void k_gather(const float* __restrict__ feat,
                                                 const float* __restrict__ cb,
                                                 const float* __restrict__ mask,
                                                 const int* __restrict__ idx,
                                                 float* __restrict__ outq,
                                                 float* __restrict__ lsum) {
  const int t = threadIdx.x;
  const int row = blockIdx.x * 4 + (t >> 6);  // 4 rows per block, 1 wave per row
  const int dg = t & 63;                      // float4 group within the row
  const int k = idx[row];
  const float4 q = ((const float4*)cb)[k * (DIM / 4) + dg];
  const float4 x = ((const float4*)feat)[(size_t)row * (DIM / 4) + dg];
  const float m = mask[row];
  float4 o;
  o.x = x.x + (q.x - x.x);
  o.y = x.y + (q.y - x.y);
  o.z = x.z + (q.z - x.z);
  o.w = x.w + (q.w - x.w);
  ((float4*)outq)[(size_t)row * (DIM / 4) + dg] = o;
  const float dx = x.x - q.x, dy = x.y - q.y, dz = x.z - q.z, dw = x.w - q.w;
  float s = m * (dx * dx + dy * dy + dz * dz + dw * dw);
  s = wave_reduce_sum(s);
  __shared__ float red[4];
  if ((t & 63) == 0) red[t >> 6] = s;
  __syncthreads();
  if (t == 0) atomicAdd(&lsum[row >> 11], red[0] + red[1] + red[2] + red[3]);
}

__global__ void k_final(const float* __restrict__ lsum,
                        const float* __restrict__ denom,
                        float* __restrict__ outl) {
  const int t = threadIdx.x;
  if (t < BATCH) {
    const float v = lsum[t] / denom[t];
    outl[t] = v;          // quant_loss
    outl[BATCH + t] = v;  // commit_loss (numerically identical in forward)
  }
}

extern "C" void kernel_launch(void* const* d_in, const int* in_sizes, int n_in,
                              void* d_out, int out_size, void* d_ws, size_t ws_size,
                              hipStream_t stream) {
  const float* feat = (const float*)d_in[0];  // [16,2048,256]
  const float* mask = (const float*)d_in[1];  // [16,2048]
  const float* cb   = (const float*)d_in[2];  // [1024,256]
  float* out = (float*)d_out;

  float* wt    = (float*)d_ws;               // [256][1024] transposed codebook (1 MB)
  float* cbsq  = wt + DIM * NCODES;          // [1024]
  int*   idx   = (int*)(cbsq + NCODES);      // [32768]
  float* denom = (float*)(idx + NROWS);      // [16]
  float* lsum  = denom + BATCH;              // [16]

  k_prep<<<NCODES, NTHR, 0, stream>>>(cb, wt, cbsq);
  k_mask<<<BATCH, NTHR, 0, stream>>>(mask, denom, lsum);
  k_argmin<<<NROWS / MROWS, NTHR, 0, stream>>>(feat, wt, cbsq, idx);
  k_gather<<<NROWS / 4, NTHR, 0, stream>>>(feat, cb, mask, idx, out, lsum);
  k_final<<<1, 64, 0, stream>>>(lsum, denom, out + (size_t)NROWS * DIM);
}

// Round 2
// 450.680 us; speedup vs baseline: 1.2042x; 1.2042x over previous
//
#include <hip/hip_runtime.h>

#define DIM    256
#define NCODES 1024
#define BATCH  16
#define SEQ    2048
#define NROWS  (BATCH * SEQ)   // 32768
#define NTHR   256
#define KP     768             // split-K': [xh | xl | xh] . [wh | wh | wl]
#define KG     (KP / 8)        // 96 groups of 8 bf16
#define MB     128             // rows per block in k_score
#define NTILE  128             // codes per N-tile
#define KCH    128             // k' per LDS chunk

typedef short short8 __attribute__((ext_vector_type(8)));
typedef float f32x4 __attribute__((ext_vector_type(4)));

__device__ __forceinline__ float wave_reduce_sum(float s) {
#pragma unroll
  for (int off = 32; off > 0; off >>= 1) s += __shfl_down(s, off, 64);
  return s;
}

// round-to-nearest-even float -> bf16 (as raw short)
__device__ __forceinline__ short f2bf(float f) {
  unsigned u = __builtin_bit_cast(unsigned, f);
  u = (u + 0x7fff + ((u >> 16) & 1)) >> 16;
  return (short)u;
}
__device__ __forceinline__ float bf2f(short s) {
  unsigned u = ((unsigned)(unsigned short)s) << 16;
  return __builtin_bit_cast(float, u);
}

// ---- prep A: feat [32768][256] f32 -> Abuf fragment-major bf16, K'=768 ----
// Abuf short8 index: (rb*KG + kg)*16 + m   (rb=row>>4, m=row&15, kg=k'/8)
// kg in [0,32): xh(k=kg*8+j); [32,64): xl(k=(kg-32)*8+j); [64,96): xh(k=(kg-64)*8+j)
__global__ __launch_bounds__(NTHR) void k_prepA(const float* __restrict__ feat,
                                                short8* __restrict__ abuf) {
  const int rb = blockIdx.x;      // 2048 row-blocks of 16 rows
  const int t = threadIdx.x;
  __shared__ float tile[16 * DIM];  // 16 KB
#pragma unroll
  for (int i = 0; i < 16; ++i) tile[i * NTHR + t] = feat[(size_t)rb * 16 * DIM + i * NTHR + t];
  __syncthreads();
#pragma unroll
  for (int it = 0; it < 6; ++it) {
    const int idx = it * NTHR + t;       // 1536 items = 96 kg x 16 m
    const int kg = idx >> 4;
    const int m = idx & 15;
    const int region = kg >> 5;          // 0:xh 1:xl 2:xh
    const int k0 = (kg & 31) * 8;
    short8 v;
#pragma unroll
    for (int j = 0; j < 8; ++j) {
      const float x = tile[m * DIM + k0 + j];
      const short h = f2bf(x);
      v[j] = (region == 1) ? f2bf(x - bf2f(h)) : h;
    }
    abuf[((size_t)rb * KG + kg) * 16 + m] = v;
  }
}

// ---- prep B: codebook [1024][256] f32 -> Bbuf staged-chunk layout bf16 ----
// Bbuf short8 index: ((nt*6 + kc)*16 + kgl)*128 + nl
//   nt=n>>7, nl=n&127, kc=kg>>4, kgl=kg&15
// kg in [0,32): wh; [32,64): wh (dup); [64,96): wl
__global__ __launch_bounds__(NTHR) void k_prepB(const float* __restrict__ cb,
                                                short8* __restrict__ bbuf) {
  const int idx = blockIdx.x * NTHR + threadIdx.x;  // 96*1024 items
  const int kg = idx >> 10;
  const int n = idx & 1023;
  const int region = kg >> 5;
  const int k0 = (kg & 31) * 8;
  short8 v;
#pragma unroll
  for (int j = 0; j < 8; ++j) {
    const float w = cb[n * DIM + k0 + j];
    const short h = f2bf(w);
    v[j] = (region == 2) ? f2bf(w - bf2f(h)) : h;
  }
  const int nt = n >> 7, nl = n & 127, kc = kg >> 4, kgl = kg & 15;
  bbuf[(((size_t)nt * 6 + kc) * 16 + kgl) * 128 + nl] = v;
}

// ---- cb_sq (exact fp32) ----
__global__ __launch_bounds__(NTHR) void k_cbsq(const float* __restrict__ cb,
                                               float* __restrict__ cbsq) {
  const int k = blockIdx.x;
  const int t = threadIdx.x;
  const float v = cb[k * DIM + t];
  float s = wave_reduce_sum(v * v);
  __shared__ float red[NTHR / 64];
  if ((t & 63) == 0) red[t >> 6] = s;
  __syncthreads();
  if (t == 0) cbsq[k] = red[0] + red[1] + red[2] + red[3];
}

// ---- denom + zero loss accumulators ----
__global__ __launch_bounds__(NTHR) void k_mask(const float* __restrict__ mask,
                                               float* __restrict__ denom,
                                               float* __restrict__ lsum) {
  const int b = blockIdx.x;
  const int t = threadIdx.x;
  float s = 0.f;
  for (int i = t; i < SEQ; i += NTHR) s += mask[b * SEQ + i];
  s = wave_reduce_sum(s);
  __shared__ float red[NTHR / 64];
  if ((t & 63) == 0) red[t >> 6] = s;
  __syncthreads();
  if (t == 0) { denom[b] = red[0] + red[1] + red[2] + red[3]; lsum[b] = 0.f; }
}

// ---- fused MFMA score + argmin ----
// Block: 4 waves, 128 rows. Wave: 32 rows (2 M-subtiles of 16).
// Loop 8 N-tiles of 128 codes; inner 6 K-chunks of 128 k' staged in LDS.
__global__ __launch_bounds__(NTHR, 3) void k_score(const short8* __restrict__ abuf,
                                                   const short8* __restrict__ bbuf,
                                                   const float* __restrict__ cbsq,
                                                   int* __restrict__ idx_out) {
  __shared__ float4 ldsB[2048];  // 32 KB: one (nt,kc) chunk, layout == Bbuf chunk
  const int tid = threadIdx.x;
  const int w = tid >> 6;
  const int lane = tid & 63;
  const int quad = lane >> 4;
  const int l15 = lane & 15;
  const int rb0 = blockIdx.x * 8 + w * 2;  // 2 consecutive row-blocks of 16 per wave

  float best[8];
  int bestk[8];
#pragma unroll
  for (int j = 0; j < 8; ++j) { best[j] = 3.4e38f; bestk[j] = 0; }

  for (int nt = 0; nt < 8; ++nt) {
    f32x4 C[2][8];
#pragma unroll
    for (int s = 0; s < 2; ++s)
#pragma unroll
      for (int n = 0; n < 8; ++n) C[s][n] = (f32x4)0.f;

    for (int kc = 0; kc < 6; ++kc) {
      __syncthreads();
      const float4* src = (const float4*)bbuf + ((size_t)nt * 6 + kc) * 2048;
#pragma unroll
      for (int i = 0; i < 8; ++i) ldsB[i * NTHR + tid] = src[i * NTHR + tid];
      // A fragments for this chunk (global, coalesced, L2/L3-hot)
      short8 a[2][4];
#pragma unroll
      for (int s = 0; s < 2; ++s)
#pragma unroll
        for (int ks = 0; ks < 4; ++ks)
          a[s][ks] = abuf[((size_t)(rb0 + s) * KG + kc * 16 + ks * 4 + quad) * 16 + l15];
      __syncthreads();
      const short8* lb = (const short8*)ldsB;
#pragma unroll
      for (int ks = 0; ks < 4; ++ks) {
#pragma unroll
        for (int n = 0; n < 8; ++n) {
          const short8 b = lb[(ks * 4 + quad) * 128 + n * 16 + l15];
          C[0][n] = __builtin_amdgcn_mfma_f32_16x16x32_bf16(a[0][ks], b, C[0][n], 0, 0, 0);
          C[1][n] = __builtin_amdgcn_mfma_f32_16x16x32_bf16(a[1][ks], b, C[1][n], 0, 0, 0);
        }
      }
    }
    // epilogue: dist = cbsq - 2*dot, update per-lane running argmin
#pragma unroll
    for (int n = 0; n < 8; ++n) {
      const int code = nt * 128 + n * 16 + l15;
      const float cs = cbsq[code];
#pragma unroll
      for (int s = 0; s < 2; ++s)
#pragma unroll
        for (int r = 0; r < 4; ++r) {
          const float dist = cs - 2.f * C[s][n][r];
          const int j = s * 4 + r;
          if (dist < best[j]) { best[j] = dist; bestk[j] = code; }
        }
    }
  }

  // cross-lane argmin over the 16 lanes sharing the same rows (same quad group)
#pragma unroll
  for (int m = 1; m < 16; m <<= 1) {
#pragma unroll
    for (int j = 0; j < 8; ++j) {
      const float od = __shfl_xor(best[j], m, 64);
      const int oi = __shfl_xor(bestk[j], m, 64);
      if (od < best[j] || (od == best[j] && oi < bestk[j])) { best[j] = od; bestk[j] = oi; }
    }
  }
  if (l15 == 0) {
#pragma unroll
    for (int j = 0; j < 8; ++j) {
      const int s = j >> 2, r = j & 3;
      const int row = blockIdx.x * MB + w * 32 + s * 16 + quad * 4 + r;
      idx_out[row] = bestk[j];
    }
  }
}

// ---- gather codes, straight-through output, masked squared-error reduce ----
__global__ __launch_bounds__(NTHR) void k_gather(const float* __restrict__ feat,
                                                 const float* __restrict__ cb,
                                                 const float* __restrict__ mask,
                                                 const int* __restrict__ idx,
                                                 float* __restrict__ outq,
                                                 float* __restrict__ lsum) {
  const int t = threadIdx.x;
  const int row = blockIdx.x * 4 + (t >> 6);
  const int dg = t & 63;
  const int k = idx[row];
  const float4 q = ((const float4*)cb)[k * (DIM / 4) + dg];
  const float4 x = ((const float4*)feat)[(size_t)row * (DIM / 4) + dg];
  const float m = mask[row];
  float4 o;
  o.x = x.x + (q.x - x.x);
  o.y = x.y + (q.y - x.y);
  o.z = x.z + (q.z - x.z);
  o.w = x.w + (q.w - x.w);
  ((float4*)outq)[(size_t)row * (DIM / 4) + dg] = o;
  const float dx = x.x - q.x, dy = x.y - q.y, dz = x.z - q.z, dw = x.w - q.w;
  float s = m * (dx * dx + dy * dy + dz * dz + dw * dw);
  s = wave_reduce_sum(s);
  __shared__ float red[4];
  if ((t & 63) == 0) red[t >> 6] = s;
  __syncthreads();
  if (t == 0) atomicAdd(&lsum[row >> 11], red[0] + red[1] + red[2] + red[3]);
}

__global__ void k_final(const float* __restrict__ lsum,
                        const float* __restrict__ denom,
                        float* __restrict__ outl) {
  const int t = threadIdx.x;
  if (t < BATCH) {
    const float v = lsum[t] / denom[t];
    outl[t] = v;          // quant_loss
    outl[BATCH + t] = v;  // commit_loss (identical in forward)
  }
}

extern "C" void kernel_launch(void* const* d_in, const int* in_sizes, int n_in,
                              void* d_out, int out_size, void* d_ws, size_t ws_size,
                              hipStream_t stream) {
  const float* feat = (const float*)d_in[0];  // [16,2048,256]
  const float* mask = (const float*)d_in[1];  // [16,2048]
  const float* cb   = (const float*)d_in[2];  // [1024,256]
  float* out = (float*)d_out;

  short8* abuf = (short8*)d_ws;                          // 32768*768*2 B = 50.3 MB
  short8* bbuf = (short8*)((char*)d_ws + (size_t)NROWS * KP * 2);  // 1.5 MB
  float* cbsq  = (float*)((char*)bbuf + (size_t)NCODES * KP * 2);  // 4 KB
  int*   idx   = (int*)(cbsq + NCODES);                  // 128 KB
  float* denom = (float*)(idx + NROWS);                  // 64 B
  float* lsum  = denom + BATCH;                          // 64 B

  k_prepA<<<NROWS / 16, NTHR, 0, stream>>>(feat, abuf);
  k_prepB<<<(NCODES * KG) / NTHR, NTHR, 0, stream>>>(cb, bbuf);
  k_cbsq<<<NCODES, NTHR, 0, stream>>>(cb, cbsq);
  k_mask<<<BATCH, NTHR, 0, stream>>>(mask, denom, lsum);
  k_score<<<NROWS / MB, NTHR, 0, stream>>>(abuf, bbuf, cbsq, idx);
  k_gather<<<NROWS / 4, NTHR, 0, stream>>>(feat, cb, mask, idx, out, lsum);
  k_final<<<1, 64, 0, stream>>>(lsum, denom, out + (size_t)NROWS * DIM);
}

// Round 3
// 270.377 us; speedup vs baseline: 2.0072x; 1.6669x over previous
//
#include <hip/hip_runtime.h>

#define DIM    256
#define NCODES 1024
#define BATCH  16
#define SEQ    2048
#define NROWS  (BATCH * SEQ)   // 32768
#define NTHR   256
#define NGRP   16              // 16 ng tiles of 64 codes

typedef short short8 __attribute__((ext_vector_type(8)));
typedef float f32x4 __attribute__((ext_vector_type(4)));

__device__ __forceinline__ float wave_reduce_sum(float s) {
#pragma unroll
  for (int off = 32; off > 0; off >>= 1) s += __shfl_down(s, off, 64);
  return s;
}

// round-to-nearest-even float -> bf16 (raw short)
__device__ __forceinline__ short f2bf(float f) {
  unsigned u = __builtin_bit_cast(unsigned, f);
  u = (u + 0x7fff + ((u >> 16) & 1)) >> 16;
  return (short)u;
}
__device__ __forceinline__ float bf2f(short s) {
  unsigned u = ((unsigned)(unsigned short)s) << 16;
  return __builtin_bit_cast(float, u);
}

// ---- prep A: feat [32768][256] f32 -> abuf fragment-major bf16, packed [xh|xl] (512 k')
// abuf short8 index: rb16*1024 + kg*16 + m   (rb16=row>>4, m=row&15, kg in [0,64))
// kg in [0,32): xh(k=kg*8+j) ; kg in [32,64): xl(k=(kg-32)*8+j)
__global__ __launch_bounds__(NTHR) void k_prepA(const float* __restrict__ feat,
                                                short8* __restrict__ abuf) {
  const int rb = blockIdx.x;   // 2048 blocks of 16 rows
  const int t = threadIdx.x;
  __shared__ float tile[16 * 257];  // +1 pad: conflict-free
  const float* src = feat + (size_t)rb * 16 * DIM;
#pragma unroll
  for (int i = 0; i < 16; ++i) tile[i * 257 + t] = src[i * DIM + t];
  __syncthreads();
#pragma unroll
  for (int it = 0; it < 4; ++it) {
    const int idx = it * NTHR + t;   // 1024 items = 64 kg x 16 m
    const int kg = idx >> 4;
    const int m = idx & 15;
    const int region = kg >> 5;      // 0:xh 1:xl
    const int k0 = (kg & 31) * 8;
    short8 v;
#pragma unroll
    for (int j = 0; j < 8; ++j) {
      const float x = tile[m * 257 + k0 + j];
      const short h = f2bf(x);
      v[j] = region ? f2bf(x - bf2f(h)) : h;
    }
    abuf[(size_t)rb * 1024 + idx] = v;
  }
}

// ---- prep B: codebook [1024][256] f32 -> bbuf packed [wh|wl] + cbsq ----
// bbuf short8 index: nb16*1024 + kg*16 + m   (nb16=code>>4, m=code&15)
// kg in [0,32): wh ; [32,64): wl
__global__ __launch_bounds__(NTHR) void k_prepB(const float* __restrict__ cb,
                                                short8* __restrict__ bbuf,
                                                float* __restrict__ cbsq) {
  const int nb = blockIdx.x;   // 64 blocks of 16 codes
  const int t = threadIdx.x;
  __shared__ float tile[16 * 257];
  const float* src = cb + (size_t)nb * 16 * DIM;
#pragma unroll
  for (int i = 0; i < 16; ++i) tile[i * 257 + t] = src[i * DIM + t];
  __syncthreads();
#pragma unroll
  for (int it = 0; it < 4; ++it) {
    const int idx = it * NTHR + t;
    const int kg = idx >> 4;
    const int m = idx & 15;
    const int region = kg >> 5;
    const int k0 = (kg & 31) * 8;
    short8 v;
#pragma unroll
    for (int j = 0; j < 8; ++j) {
      const float w = tile[m * 257 + k0 + j];
      const short h = f2bf(w);
      v[j] = region ? f2bf(w - bf2f(h)) : h;
    }
    bbuf[(size_t)nb * 1024 + idx] = v;
  }
  if (t < 16) {
    float s = 0.f;
    for (int c = 0; c < DIM; ++c) { const float w = tile[t * 257 + c]; s = fmaf(w, w, s); }
    cbsq[nb * 16 + t] = s;
  }
}

// ---- denom + zero loss accumulators ----
__global__ __launch_bounds__(NTHR) void k_mask(const float* __restrict__ mask,
                                               float* __restrict__ denom,
                                               float* __restrict__ lsum) {
  const int b = blockIdx.x;
  const int t = threadIdx.x;
  float s = 0.f;
  for (int i = t; i < SEQ; i += NTHR) s += mask[b * SEQ + i];
  s = wave_reduce_sum(s);
  __shared__ float red[NTHR / 64];
  if ((t & 63) == 0) red[t >> 6] = s;
  __syncthreads();
  if (t == 0) { denom[b] = red[0] + red[1] + red[2] + red[3]; lsum[b] = 0.f; }
}

// ---- barrier-free MFMA score + partial argmin ----
// Wave tile: 64 rows x 64 codes. K' = 768 via 24 k-steps of 32, regions:
//   s in [0,8):  xh.wh    s in [8,16): xl.wh    s in [16,24): xh.wl
// A index re-map: ka = s<16 ? s : s-16   (abuf holds [xh|xl] = 16 steps)
// B index re-map: kb = s<8  ? s : s-8    (bbuf holds [wh|wl] = 16 steps)
// Block = 4 waves = 2 rg x 2 ng (L1 sharing of A and B).
__global__ __launch_bounds__(NTHR, 3) void k_score(const short8* __restrict__ abuf,
                                                   const short8* __restrict__ bbuf,
                                                   const float* __restrict__ cbsq,
                                                   float* __restrict__ pdist,
                                                   int* __restrict__ pidx) {
  const int t = threadIdx.x;
  const int w = t >> 6;
  const int lane = t & 63;
  const int l15 = lane & 15;
  const int quad = lane >> 4;
  const int by = blockIdx.x & 255;   // rg-pair: XCD = blockIdx%8 = by%8 -> A slice ~4MB/XCD
  const int bx = blockIdx.x >> 8;    // ng-pair
  const int rg = by * 2 + (w >> 1);  // [0,512): 64-row group
  const int ng = bx * 2 + (w & 1);   // [0,16):  64-code group

  const short8* __restrict__ Ap = abuf + (size_t)rg * 4096 + quad * 16 + l15;
  const short8* __restrict__ Bp = bbuf + (size_t)ng * 4096 + quad * 16 + l15;

  f32x4 C[4][4];
#pragma unroll
  for (int mi = 0; mi < 4; ++mi)
#pragma unroll
    for (int ni = 0; ni < 4; ++ni) C[mi][ni] = (f32x4)0.f;

#pragma unroll 2
  for (int s = 0; s < 24; ++s) {
    const int ka = (s < 16 ? s : s - 16) * 64;
    const int kb = (s < 8 ? s : s - 8) * 64;
    short8 a[4], b[4];
#pragma unroll
    for (int mi = 0; mi < 4; ++mi) a[mi] = Ap[mi * 1024 + ka];
#pragma unroll
    for (int ni = 0; ni < 4; ++ni) b[ni] = Bp[ni * 1024 + kb];
#pragma unroll
    for (int mi = 0; mi < 4; ++mi)
#pragma unroll
      for (int ni = 0; ni < 4; ++ni)
        C[mi][ni] = __builtin_amdgcn_mfma_f32_16x16x32_bf16(a[mi], b[ni], C[mi][ni], 0, 0, 0);
  }

  // dist = cbsq - 2*dot ; per-lane reduce over ni, then over the 16 lanes of each row
  float cs[4];
#pragma unroll
  for (int ni = 0; ni < 4; ++ni) cs[ni] = cbsq[ng * 64 + ni * 16 + l15];

  float best[16];
  int bidx[16];
#pragma unroll
  for (int mi = 0; mi < 4; ++mi)
#pragma unroll
    for (int r = 0; r < 4; ++r) {
      float bd = 3.4e38f;
      int bi = 0;
#pragma unroll
      for (int ni = 0; ni < 4; ++ni) {
        const float d = fmaf(-2.f, C[mi][ni][r], cs[ni]);
        const int code = ng * 64 + ni * 16 + l15;
        if (d < bd) { bd = d; bi = code; }  // ni ascending + strict < => smallest idx
      }
      best[mi * 4 + r] = bd;
      bidx[mi * 4 + r] = bi;
    }
#pragma unroll
  for (int m = 1; m <= 8; m <<= 1) {
#pragma unroll
    for (int j = 0; j < 16; ++j) {
      const float od = __shfl_xor(best[j], m, 64);
      const int oi = __shfl_xor(bidx[j], m, 64);
      if (od < best[j] || (od == best[j] && oi < bidx[j])) { best[j] = od; bidx[j] = oi; }
    }
  }
  if (l15 == 0) {
#pragma unroll
    for (int mi = 0; mi < 4; ++mi)
#pragma unroll
      for (int r = 0; r < 4; ++r) {
        const int row = rg * 64 + mi * 16 + quad * 4 + r;  // C-layout: row=(lane>>4)*4+reg
        pdist[row * NGRP + ng] = best[mi * 4 + r];
        pidx[row * NGRP + ng] = bidx[mi * 4 + r];
      }
  }
}

// ---- merge partials + gather + straight-through out + masked MSE reduce ----
__global__ __launch_bounds__(NTHR) void k_gather(const float* __restrict__ feat,
                                                 const float* __restrict__ cb,
                                                 const float* __restrict__ mask,
                                                 const float* __restrict__ pdist,
                                                 const int* __restrict__ pidx,
                                                 float* __restrict__ outq,
                                                 float* __restrict__ lsum) {
  const int t = threadIdx.x;
  const int row = blockIdx.x * 4 + (t >> 6);
  const int lane = t & 63;
  float d = pdist[row * NGRP + (lane & 15)];
  int ki = pidx[row * NGRP + (lane & 15)];
#pragma unroll
  for (int m = 1; m <= 8; m <<= 1) {
    const float od = __shfl_xor(d, m, 64);
    const int oi = __shfl_xor(ki, m, 64);
    if (od < d || (od == d && oi < ki)) { d = od; ki = oi; }
  }
  const int k = __shfl(ki, 0, 64);
  const float4 q = ((const float4*)cb)[k * (DIM / 4) + lane];
  const float4 x = ((const float4*)feat)[(size_t)row * (DIM / 4) + lane];
  const float m = mask[row];
  float4 o;
  o.x = x.x + (q.x - x.x);
  o.y = x.y + (q.y - x.y);
  o.z = x.z + (q.z - x.z);
  o.w = x.w + (q.w - x.w);
  ((float4*)outq)[(size_t)row * (DIM / 4) + lane] = o;
  const float dx = x.x - q.x, dy = x.y - q.y, dz = x.z - q.z, dw = x.w - q.w;
  float s = m * (dx * dx + dy * dy + dz * dz + dw * dw);
  s = wave_reduce_sum(s);
  __shared__ float red[4];
  if ((t & 63) == 0) red[t >> 6] = s;
  __syncthreads();
  if (t == 0) atomicAdd(&lsum[row >> 11], red[0] + red[1] + red[2] + red[3]);
}

__global__ void k_final(const float* __restrict__ lsum,
                        const float* __restrict__ denom,
                        float* __restrict__ outl) {
  const int t = threadIdx.x;
  if (t < BATCH) {
    const float v = lsum[t] / denom[t];
    outl[t] = v;          // quant_loss
    outl[BATCH + t] = v;  // commit_loss (identical in forward)
  }
}

extern "C" void kernel_launch(void* const* d_in, const int* in_sizes, int n_in,
                              void* d_out, int out_size, void* d_ws, size_t ws_size,
                              hipStream_t stream) {
  const float* feat = (const float*)d_in[0];  // [16,2048,256]
  const float* mask = (const float*)d_in[1];  // [16,2048]
  const float* cb   = (const float*)d_in[2];  // [1024,256]
  float* out = (float*)d_out;

  char* p = (char*)d_ws;
  short8* abuf = (short8*)p;                 p += (size_t)NROWS * 512 * 2;   // 33.55 MB
  short8* bbuf = (short8*)p;                 p += (size_t)NCODES * 512 * 2;  // 1.05 MB
  float* cbsq  = (float*)p;                  p += NCODES * 4;
  float* pdist = (float*)p;                  p += (size_t)NROWS * NGRP * 4;  // 2 MB
  int*   pidx  = (int*)p;                    p += (size_t)NROWS * NGRP * 4;  // 2 MB
  float* denom = (float*)p;                  p += BATCH * 4;
  float* lsum  = (float*)p;

  k_prepA<<<NROWS / 16, NTHR, 0, stream>>>(feat, abuf);
  k_prepB<<<NCODES / 16, NTHR, 0, stream>>>(cb, bbuf, cbsq);
  k_mask<<<BATCH, NTHR, 0, stream>>>(mask, denom, lsum);
  k_score<<<2048, NTHR, 0, stream>>>(abuf, bbuf, cbsq, pdist, pidx);
  k_gather<<<NROWS / 4, NTHR, 0, stream>>>(feat, cb, mask, pdist, pidx, out, lsum);
  k_final<<<1, 64, 0, stream>>>(lsum, denom, out + (size_t)NROWS * DIM);
}

// Round 4
// 178.891 us; speedup vs baseline: 3.0337x; 1.5114x over previous
//
#include <hip/hip_runtime.h>

#define DIM    256
#define NCODES 1024
#define BATCH  16
#define SEQ    2048
#define NROWS  (BATCH * SEQ)   // 32768
#define NTHR   256
#define NGRP   16              // 16 ng tiles of 64 codes

typedef short short8 __attribute__((ext_vector_type(8)));
typedef float f32x4 __attribute__((ext_vector_type(4)));

__device__ __forceinline__ float wave_reduce_sum(float s) {
#pragma unroll
  for (int off = 32; off > 0; off >>= 1) s += __shfl_down(s, off, 64);
  return s;
}

// round-to-nearest-even float -> bf16 (raw short)
__device__ __forceinline__ short f2bf(float f) {
  unsigned u = __builtin_bit_cast(unsigned, f);
  u = (u + 0x7fff + ((u >> 16) & 1)) >> 16;
  return (short)u;
}
__device__ __forceinline__ float bf2f(short s) {
  unsigned u = ((unsigned)(unsigned short)s) << 16;
  return __builtin_bit_cast(float, u);
}

// ---- prep A: feat [32768][256] f32 -> abuf fragment-major bf16, packed [xh|xl] (512 k')
// abuf short8 index: rb16*1024 + kg*16 + m   (rb16=row>>4, m=row&15, kg in [0,64))
// kg in [0,32): xh(k=kg*8+j) ; kg in [32,64): xl(k=(kg-32)*8+j)
__global__ __launch_bounds__(NTHR) void k_prepA(const float* __restrict__ feat,
                                                short8* __restrict__ abuf) {
  const int rb = blockIdx.x;   // 2048 blocks of 16 rows
  const int t = threadIdx.x;
  __shared__ float tile[16 * 257];  // +1 pad: conflict-free
  const float* src = feat + (size_t)rb * 16 * DIM;
#pragma unroll
  for (int i = 0; i < 16; ++i) tile[i * 257 + t] = src[i * DIM + t];
  __syncthreads();
#pragma unroll
  for (int it = 0; it < 4; ++it) {
    const int idx = it * NTHR + t;   // 1024 items = 64 kg x 16 m
    const int kg = idx >> 4;
    const int m = idx & 15;
    const int region = kg >> 5;      // 0:xh 1:xl
    const int k0 = (kg & 31) * 8;
    short8 v;
#pragma unroll
    for (int j = 0; j < 8; ++j) {
      const float x = tile[m * 257 + k0 + j];
      const short h = f2bf(x);
      v[j] = region ? f2bf(x - bf2f(h)) : h;
    }
    abuf[(size_t)rb * 1024 + idx] = v;
  }
}

// ---- prep B: codebook [1024][256] f32 -> bbuf packed [wh|wl] + cbsq ----
__global__ __launch_bounds__(NTHR) void k_prepB(const float* __restrict__ cb,
                                                short8* __restrict__ bbuf,
                                                float* __restrict__ cbsq) {
  const int nb = blockIdx.x;   // 64 blocks of 16 codes
  const int t = threadIdx.x;
  __shared__ float tile[16 * 257];
  const float* src = cb + (size_t)nb * 16 * DIM;
#pragma unroll
  for (int i = 0; i < 16; ++i) tile[i * 257 + t] = src[i * DIM + t];
  __syncthreads();
#pragma unroll
  for (int it = 0; it < 4; ++it) {
    const int idx = it * NTHR + t;
    const int kg = idx >> 4;
    const int m = idx & 15;
    const int region = kg >> 5;
    const int k0 = (kg & 31) * 8;
    short8 v;
#pragma unroll
    for (int j = 0; j < 8; ++j) {
      const float w = tile[m * 257 + k0 + j];
      const short h = f2bf(w);
      v[j] = region ? f2bf(w - bf2f(h)) : h;
    }
    bbuf[(size_t)nb * 1024 + idx] = v;
  }
  if (t < 16) {
    float s = 0.f;
    for (int c = 0; c < DIM; ++c) { const float w = tile[t * 257 + c]; s = fmaf(w, w, s); }
    cbsq[nb * 16 + t] = s;
  }
}

// ---- denom + zero loss accumulators ----
__global__ __launch_bounds__(NTHR) void k_mask(const float* __restrict__ mask,
                                               float* __restrict__ denom,
                                               float* __restrict__ lsum) {
  const int b = blockIdx.x;
  const int t = threadIdx.x;
  float s = 0.f;
  for (int i = t; i < SEQ; i += NTHR) s += mask[b * SEQ + i];
  s = wave_reduce_sum(s);
  __shared__ float red[NTHR / 64];
  if ((t & 63) == 0) red[t >> 6] = s;
  __syncthreads();
  if (t == 0) { denom[b] = red[0] + red[1] + red[2] + red[3]; lsum[b] = 0.f; }
}

// ---- barrier-free MFMA score + partial argmin (unchanged from round 3) ----
__global__ __launch_bounds__(NTHR, 3) void k_score(const short8* __restrict__ abuf,
                                                   const short8* __restrict__ bbuf,
                                                   const float* __restrict__ cbsq,
                                                   float* __restrict__ pdist,
                                                   int* __restrict__ pidx) {
  const int t = threadIdx.x;
  const int w = t >> 6;
  const int lane = t & 63;
  const int l15 = lane & 15;
  const int quad = lane >> 4;
  const int by = blockIdx.x & 255;   // rg-pair: XCD striping via blockIdx%8
  const int bx = blockIdx.x >> 8;    // ng-pair
  const int rg = by * 2 + (w >> 1);  // [0,512): 64-row group
  const int ng = bx * 2 + (w & 1);   // [0,16):  64-code group

  const short8* __restrict__ Ap = abuf + (size_t)rg * 4096 + quad * 16 + l15;
  const short8* __restrict__ Bp = bbuf + (size_t)ng * 4096 + quad * 16 + l15;

  f32x4 C[4][4];
#pragma unroll
  for (int mi = 0; mi < 4; ++mi)
#pragma unroll
    for (int ni = 0; ni < 4; ++ni) C[mi][ni] = (f32x4)0.f;

#pragma unroll 2
  for (int s = 0; s < 24; ++s) {
    const int ka = (s < 16 ? s : s - 16) * 64;
    const int kb = (s < 8 ? s : s - 8) * 64;
    short8 a[4], b[4];
#pragma unroll
    for (int mi = 0; mi < 4; ++mi) a[mi] = Ap[mi * 1024 + ka];
#pragma unroll
    for (int ni = 0; ni < 4; ++ni) b[ni] = Bp[ni * 1024 + kb];
#pragma unroll
    for (int mi = 0; mi < 4; ++mi)
#pragma unroll
      for (int ni = 0; ni < 4; ++ni)
        C[mi][ni] = __builtin_amdgcn_mfma_f32_16x16x32_bf16(a[mi], b[ni], C[mi][ni], 0, 0, 0);
  }

  float cs[4];
#pragma unroll
  for (int ni = 0; ni < 4; ++ni) cs[ni] = cbsq[ng * 64 + ni * 16 + l15];

  float best[16];
  int bidx[16];
#pragma unroll
  for (int mi = 0; mi < 4; ++mi)
#pragma unroll
    for (int r = 0; r < 4; ++r) {
      float bd = 3.4e38f;
      int bi = 0;
#pragma unroll
      for (int ni = 0; ni < 4; ++ni) {
        const float d = fmaf(-2.f, C[mi][ni][r], cs[ni]);
        const int code = ng * 64 + ni * 16 + l15;
        if (d < bd) { bd = d; bi = code; }
      }
      best[mi * 4 + r] = bd;
      bidx[mi * 4 + r] = bi;
    }
#pragma unroll
  for (int m = 1; m <= 8; m <<= 1) {
#pragma unroll
    for (int j = 0; j < 16; ++j) {
      const float od = __shfl_xor(best[j], m, 64);
      const int oi = __shfl_xor(bidx[j], m, 64);
      if (od < best[j] || (od == best[j] && oi < bidx[j])) { best[j] = od; bidx[j] = oi; }
    }
  }
  if (l15 == 0) {
#pragma unroll
    for (int mi = 0; mi < 4; ++mi)
#pragma unroll
      for (int r = 0; r < 4; ++r) {
        const int row = rg * 64 + mi * 16 + quad * 4 + r;
        pdist[row * NGRP + ng] = best[mi * 4 + r];
        pidx[row * NGRP + ng] = bidx[mi * 4 + r];
      }
  }
}

// ---- fused merge + gather + straight-through out + masked MSE ----
// Block = 64 rows. Phase 1: LDS-tree merge of 16 partials/row (coalesced f4 loads).
// Phase 2: thread = 1 dim-group x 16 rows -> 32 indep loads + 16 stores in flight.
// One atomicAdd per block.
__global__ __launch_bounds__(NTHR) void k_gather(const float* __restrict__ feat,
                                                 const float* __restrict__ cb,
                                                 const float* __restrict__ mask,
                                                 const float* __restrict__ pdist,
                                                 const int* __restrict__ pidx,
                                                 float* __restrict__ outq,
                                                 float* __restrict__ lsum) {
  const int t = threadIdx.x;
  const int row0 = blockIdx.x * 64;
  __shared__ float sd[NTHR];
  __shared__ int si[NTHR];
  __shared__ int skid[64];
  // phase 1a: thread t reduces quarter (t&3) of row (t>>2)
  {
    const float4 pd = ((const float4*)pdist)[row0 * 4 + t];
    const int4 pi = ((const int4*)pidx)[row0 * 4 + t];
    float bd = pd.x; int bi = pi.x;
    if (pd.y < bd || (pd.y == bd && pi.y < bi)) { bd = pd.y; bi = pi.y; }
    if (pd.z < bd || (pd.z == bd && pi.z < bi)) { bd = pd.z; bi = pi.z; }
    if (pd.w < bd || (pd.w == bd && pi.w < bi)) { bd = pd.w; bi = pi.w; }
    sd[t] = bd; si[t] = bi;
  }
  __syncthreads();
  // phase 1b: one thread per row merges its 4 quarters
  if (t < 64) {
    float bd = sd[t * 4]; int bi = si[t * 4];
#pragma unroll
    for (int j = 1; j < 4; ++j) {
      const float od = sd[t * 4 + j]; const int oi = si[t * 4 + j];
      if (od < bd || (od == bd && oi < bi)) { bd = od; bi = oi; }
    }
    skid[t] = bi;
  }
  __syncthreads();
  // phase 2: gather + write + loss
  const int wv = t >> 6;   // wave -> rows wv*16 .. wv*16+15
  const int dg = t & 63;   // float4 dim group
  const int b = row0 >> 11;
  float acc = 0.f;
#pragma unroll
  for (int i = 0; i < 16; ++i) {
    const int r = wv * 16 + i;
    const size_t row = row0 + r;
    const int k = skid[r];
    const float4 q = ((const float4*)cb)[k * (DIM / 4) + dg];
    const float4 x = ((const float4*)feat)[row * (DIM / 4) + dg];
    float4 o;
    o.x = x.x + (q.x - x.x);
    o.y = x.y + (q.y - x.y);
    o.z = x.z + (q.z - x.z);
    o.w = x.w + (q.w - x.w);
    ((float4*)outq)[row * (DIM / 4) + dg] = o;
    const float m = mask[row];
    const float dx = x.x - q.x, dy = x.y - q.y, dz = x.z - q.z, dw = x.w - q.w;
    acc = fmaf(m, dx * dx + dy * dy + dz * dz + dw * dw, acc);
  }
  acc = wave_reduce_sum(acc);
  __shared__ float red[4];
  if ((t & 63) == 0) red[wv] = acc;
  __syncthreads();
  if (t == 0) atomicAdd(&lsum[b], red[0] + red[1] + red[2] + red[3]);
}

__global__ void k_final(const float* __restrict__ lsum,
                        const float* __restrict__ denom,
                        float* __restrict__ outl) {
  const int t = threadIdx.x;
  if (t < BATCH) {
    const float v = lsum[t] / denom[t];
    outl[t] = v;          // quant_loss
    outl[BATCH + t] = v;  // commit_loss (identical in forward)
  }
}

extern "C" void kernel_launch(void* const* d_in, const int* in_sizes, int n_in,
                              void* d_out, int out_size, void* d_ws, size_t ws_size,
                              hipStream_t stream) {
  const float* feat = (const float*)d_in[0];  // [16,2048,256]
  const float* mask = (const float*)d_in[1];  // [16,2048]
  const float* cb   = (const float*)d_in[2];  // [1024,256]
  float* out = (float*)d_out;

  char* p = (char*)d_ws;
  short8* abuf = (short8*)p;                 p += (size_t)NROWS * 512 * 2;   // 33.55 MB
  short8* bbuf = (short8*)p;                 p += (size_t)NCODES * 512 * 2;  // 1.05 MB
  float* cbsq  = (float*)p;                  p += NCODES * 4;
  float* pdist = (float*)p;                  p += (size_t)NROWS * NGRP * 4;  // 2 MB
  int*   pidx  = (int*)p;                    p += (size_t)NROWS * NGRP * 4;  // 2 MB
  float* denom = (float*)p;                  p += BATCH * 4;
  float* lsum  = (float*)p;

  k_prepA<<<NROWS / 16, NTHR, 0, stream>>>(feat, abuf);
  k_prepB<<<NCODES / 16, NTHR, 0, stream>>>(cb, bbuf, cbsq);
  k_mask<<<BATCH, NTHR, 0, stream>>>(mask, denom, lsum);
  k_score<<<2048, NTHR, 0, stream>>>(abuf, bbuf, cbsq, pdist, pidx);
  k_gather<<<NROWS / 64, NTHR, 0, stream>>>(feat, cb, mask, pdist, pidx, out, lsum);
  k_final<<<1, 64, 0, stream>>>(lsum, denom, out + (size_t)NROWS * DIM);
}